// Round 5
// baseline (309.625 us; speedup 1.0000x reference)
//
#include <hip/hip_runtime.h>
#include <hip/hip_bf16.h>

#define HDIM 128

typedef __attribute__((ext_vector_type(8))) short short8;
typedef __attribute__((ext_vector_type(4))) float floatx4;

__device__ __forceinline__ float bf2f(unsigned short u) {
    return __uint_as_float(((unsigned)u) << 16);
}
__device__ __forceinline__ unsigned short f2b(float f) {
    __hip_bfloat16 h = __float2bfloat16(f);
    return __builtin_bit_cast(unsigned short, h);
}
__device__ __forceinline__ float ldv(const void* p, size_t i, int flag) {
    return flag ? bf2f(((const unsigned short*)p)[i]) : ((const float*)p)[i];
}
__device__ __forceinline__ short8 pack8(float4 a, float4 b) {
    short8 r;
    r[0] = (short)f2b(a.x); r[1] = (short)f2b(a.y);
    r[2] = (short)f2b(a.z); r[3] = (short)f2b(a.w);
    r[4] = (short)f2b(b.x); r[5] = (short)f2b(b.y);
    r[6] = (short)f2b(b.z); r[7] = (short)f2b(b.w);
    return r;
}

// ---------------------------------------------------------------------------
// Block-local dtype detect. flag=1 -> bf16, 0 -> f32.
// ---------------------------------------------------------------------------
__device__ __forceinline__ int local_detect_s(const unsigned short* zbits, int* red) {
    int tid = threadIdx.x;
    int nthr = blockDim.x;
    int cnt = 0;
    for (int i = tid; i < 4096; i += nthr) {
        int ex = (zbits[i] >> 7) & 0xFF;
        if (ex >= 100 && ex <= 140) cnt++;
    }
    red[tid] = cnt;
    __syncthreads();
    for (int s = nthr >> 1; s > 0; s >>= 1) {
        if (tid < s) red[tid] += red[tid + s];
        __syncthreads();
    }
    int f = (red[0] >= 3686) ? 1 : 0;
    __syncthreads();
    return f;
}

__device__ __forceinline__ int local_detect(const unsigned short* zbits) {
    __shared__ int red[256];
    return local_detect_s(zbits, red);
}

// ---------------------------------------------------------------------------
// prep: blocks 0-31 build swizzled transposed 128x128 bf16 W images with
// COALESCED source reads (scattered 2B writes are fire-and-forget).
// img[im][n*128 + ((k>>3)^(n&15))*8 + (k&7)] = w1[(part*128+k)*128 + n]
// im: 0=gd_top(k=src) 1=gd_bot(k=dst) 2=gg_top 3=gg_bot.
// Block 32: params to f32 + flag:
// [0:128)=b1_gd [128:256)=w2_gd [256:384)=b1_gg [384:512)=w2_gg
// [512]=b2_gd [513]=b2_gg        (verified r0-r2)
// ---------------------------------------------------------------------------
__global__ __launch_bounds__(256) void prep_kernel(
    const unsigned short* __restrict__ zbits,
    const void* __restrict__ w1_gd, const void* __restrict__ w1_gg,
    const void* __restrict__ b1_gd, const void* __restrict__ w2_gd,
    const void* __restrict__ b2_gd, const void* __restrict__ b1_gg,
    const void* __restrict__ w2_gg, const void* __restrict__ b2_gg,
    unsigned short* __restrict__ img, float* __restrict__ params,
    int* __restrict__ flagout)
{
    int flag = local_detect(zbits);
    int b = blockIdx.x;
    int tid = threadIdx.x;
    if (b < 32) {
        int im   = b >> 3;          // image id
        int sub  = b & 7;           // 16 k-rows per sub-block
        const void* w1 = (im < 2) ? w1_gd : w1_gg;
        int part = im & 1;
        unsigned short* out = img + im * 16384;
        int n = tid & 127;
#pragma unroll
        for (int it = 0; it < 8; ++it) {
            int k = sub * 16 + it * 2 + (tid >> 7);
            unsigned short v = flag
                ? ((const unsigned short*)w1)[(size_t)(part * 128 + k) * 128 + n]
                : f2b(((const float*)w1)[(size_t)(part * 128 + k) * 128 + n]);
            out[n * 128 + (((k >> 3) ^ (n & 15)) << 3) + (k & 7)] = v;
        }
    } else {
        if (tid < 128) {
            params[tid]       = ldv(b1_gd, tid, flag);
            params[256 + tid] = ldv(b1_gg, tid, flag);
        } else {
            params[tid]       = ldv(w2_gd, tid - 128, flag);
            params[256 + tid] = ldv(w2_gg, tid - 128, flag);
        }
        if (tid == 0) {
            params[512] = ldv(b2_gd, 0, flag);
            params[513] = ldv(b2_gg, 0, flag);
            *flagout = flag;
        }
    }
}

// ---------------------------------------------------------------------------
// fused_edge: per-edge full MLP via MFMA — proj dispatch ELIMINATED.
// out[e] = relu([zsrc;zdst].W1 + b1).w2 + b2
// 512 threads = 8 waves; 16 edges/wave -> 128 edges/block.
// Per block: stage rel's two swizzled W images (64KB) into LDS via LINEAR
// copy (conflict-free, L2-broadcast); per lane gather the exact B-fragment
// chunks of zsrc/zdst (same 8x16B/lane random-gather pattern as the old
// edge kernel, but from the 30.7MB z tables instead of 82MB A/B tables);
// 64 MFMAs (8 kc x 8 ntile); epilogue: h=acc+b1, relu, dot w2, quad-reduce
// via shfl_xor(16|32).  MFMA fragment mapping identical to verified proj:
//   B-frag lane(nl,quad) kc: z[row(nl)][kc*32+quad*8 ..+8)   (kc<4:src, >=4:dst)
//   A-frag: sW[half][ (nt*16+nl)*16 + ((kc&3)*4+quad)^nl ]
//   C: col=edge=nl, row = quad*4+reg  -> h[edge][nt*16+quad*4+reg]
// ---------------------------------------------------------------------------
__global__ __launch_bounds__(512, 4) void fused_edge_kernel(
    const void* __restrict__ Zg, const void* __restrict__ Zd,
    const int* __restrict__ edges_gd, const int* __restrict__ edges_gg,
    const uint4* __restrict__ Wimg, const float* __restrict__ params,
    void* __restrict__ out, int E, int nbe, const int* __restrict__ flagp)
{
    __shared__ uint4 sW[4096];   // 64 KB: this relation's W1 (two half images)
    int tid  = threadIdx.x;
    int lane = tid & 63;
    int wave = tid >> 6;
    int nl   = lane & 15;   // edge within tile
    int quad = lane >> 4;   // k-subslice / out-channel subslice
    int flag = *flagp;

    int rel = ((int)blockIdx.x >= nbe) ? 1 : 0;
    int blk = blockIdx.x - rel * nbe;
    const int* edges = rel ? edges_gg : edges_gd;
    const void* Zdst = rel ? Zg : Zd;

    // ---- stage W images: linear copy, conflict-free -----------------------
    const uint4* im = Wimg + rel * 4096;
#pragma unroll
    for (int i = 0; i < 8; ++i) sW[tid + i * 512] = im[tid + i * 512];

    // ---- edge indices + B-fragment gathers --------------------------------
    int e  = blk * 128 + wave * 16 + nl;
    int ec = e < E ? e : E - 1;
    int src = edges[ec];
    int dst = edges[E + ec];

    short8 zf[8];
    if (flag) {
        const uint4* zs = (const uint4*)Zg   + (size_t)src * 16;
        const uint4* zd = (const uint4*)Zdst + (size_t)dst * 16;
#pragma unroll
        for (int kc = 0; kc < 4; ++kc) {
            zf[kc]     = __builtin_bit_cast(short8, zs[kc * 4 + quad]);
            zf[kc + 4] = __builtin_bit_cast(short8, zd[kc * 4 + quad]);
        }
    } else {
        const float4* zs = (const float4*)Zg   + (size_t)src * 32;
        const float4* zd = (const float4*)Zdst + (size_t)dst * 32;
#pragma unroll
        for (int kc = 0; kc < 4; ++kc) {
            int o = kc * 8 + quad * 2;
            zf[kc]     = pack8(zs[o], zs[o + 1]);
            zf[kc + 4] = pack8(zd[o], zd[o + 1]);
        }
    }

    __syncthreads();   // W staged

    // ---- MFMA: h[16 edges][128] ------------------------------------------
    floatx4 acc[8];
#pragma unroll
    for (int nt = 0; nt < 8; ++nt) acc[nt] = (floatx4){0.f, 0.f, 0.f, 0.f};

#pragma unroll
    for (int kc = 0; kc < 8; ++kc) {
        const uint4* base = sW + (kc >> 2) * 2048;
        int p = ((kc & 3) * 4 + quad) ^ nl;   // undo XOR swizzle
#pragma unroll
        for (int nt = 0; nt < 8; ++nt) {
            short8 wf = __builtin_bit_cast(short8, base[(nt * 16 + nl) * 16 + p]);
            acc[nt] = __builtin_amdgcn_mfma_f32_16x16x32_bf16(wf, zf[kc], acc[nt], 0, 0, 0);
        }
    }

    // ---- epilogue: bias + relu + dot(w2) + quad reduce --------------------
    const float* pr = params + rel * 256;   // [0:128)=b1, [128:256)=w2
    float b2 = params[512 + rel];
    float s = 0.f;
#pragma unroll
    for (int nt = 0; nt < 8; ++nt) {
        float4 b1v = *(const float4*)(pr + nt * 16 + quad * 4);
        float4 w2v = *(const float4*)(pr + 128 + nt * 16 + quad * 4);
        s = fmaf(fmaxf(acc[nt][0] + b1v.x, 0.f), w2v.x, s);
        s = fmaf(fmaxf(acc[nt][1] + b1v.y, 0.f), w2v.y, s);
        s = fmaf(fmaxf(acc[nt][2] + b1v.z, 0.f), w2v.z, s);
        s = fmaf(fmaxf(acc[nt][3] + b1v.w, 0.f), w2v.w, s);
    }
    s += __shfl_xor(s, 16);
    s += __shfl_xor(s, 32);

    if (quad == 0 && e < E) {
        float r = s + b2;
        size_t base = (size_t)rel * E;
        if (flag) ((unsigned short*)out)[base + e] = f2b(r);
        else      ((float*)out)[base + e] = r;
    }
}

// ---------------------------------------------------------------------------
// Fallback path (ws too small): detect + full per-edge MLP, one edge/block.
// ---------------------------------------------------------------------------
__global__ __launch_bounds__(256) void detect_kernel(
    const unsigned short* __restrict__ zbits, int* __restrict__ flag)
{
    int f = local_detect(zbits);
    if (threadIdx.x == 0) *flag = f;
}

__global__ __launch_bounds__(128) void naive_edge_kernel(
    const int* __restrict__ edges,
    const void* __restrict__ zsrc, const void* __restrict__ zdst,
    const void* __restrict__ w1, const void* __restrict__ b1,
    const void* __restrict__ w2, const void* __restrict__ b2,
    void* __restrict__ out, size_t eoff, int E,
    const int* __restrict__ flagp)
{
    int flag = flagp ? *flagp : 0;
    __shared__ float zs[128], zd[128], red[128];
    int e = blockIdx.x;
    int n = threadIdx.x;
    int src = edges[e], dst = edges[E + e];
    zs[n] = ldv(zsrc, (size_t)src * HDIM + n, flag);
    zd[n] = ldv(zdst, (size_t)dst * HDIM + n, flag);
    __syncthreads();
    float acc = ldv(b1, n, flag);
    for (int k = 0; k < 128; ++k) acc = fmaf(zs[k], ldv(w1, (size_t)k * HDIM + n, flag), acc);
    for (int k = 0; k < 128; ++k) acc = fmaf(zd[k], ldv(w1, (size_t)(128 + k) * HDIM + n, flag), acc);
    red[n] = fmaxf(acc, 0.f) * ldv(w2, n, flag);
    __syncthreads();
    for (int s = 64; s > 0; s >>= 1) {
        if (n < s) red[n] += red[n + s];
        __syncthreads();
    }
    if (n == 0) {
        float r = red[0] + ldv(b2, 0, flag);
        if (flag) ((unsigned short*)out)[eoff + e] = f2b(r);
        else      ((float*)out)[eoff + e] = r;
    }
}

extern "C" void kernel_launch(void* const* d_in, const int* in_sizes, int n_in,
                              void* d_out, int out_size, void* d_ws, size_t ws_size,
                              hipStream_t stream)
{
    const void* z_gene = d_in[0];
    const void* z_dis  = d_in[1];
    const int* edges_gd = (const int*)d_in[2];
    const int* edges_gg = (const int*)d_in[3];
    const void* w1_gd = d_in[4];
    const void* b1_gd = d_in[5];
    const void* w2_gd = d_in[6];
    const void* b2_gd = d_in[7];
    const void* w1_gg = d_in[8];
    const void* b1_gg = d_in[9];
    const void* w2_gg = d_in[10];
    const void* b2_gg = d_in[11];

    int NG = in_sizes[0] / HDIM;   // 100000  (unused in fast path sizing)
    int ND = in_sizes[1] / HDIM;   // 20000
    int E  = in_sizes[2] / 2;      // 500000
    (void)NG; (void)ND;

    // workspace layout (bytes)
    size_t off_flag   = 0;
    size_t off_params = 256;
    size_t off_img    = 2560;
    size_t need       = off_img + 131072;   // flag + params + 4 W images

    char* ws = (char*)d_ws;

    if (ws_size < need) {
        const int* flagp = nullptr;
        if (ws_size >= 16) {
            detect_kernel<<<1, 256, 0, stream>>>((const unsigned short*)z_gene, (int*)ws);
            flagp = (const int*)ws;
        }
        naive_edge_kernel<<<E, 128, 0, stream>>>(edges_gd, z_gene, z_dis,
                                                 w1_gd, b1_gd, w2_gd, b2_gd,
                                                 d_out, 0, E, flagp);
        naive_edge_kernel<<<E, 128, 0, stream>>>(edges_gg, z_gene, z_gene,
                                                 w1_gg, b1_gg, w2_gg, b2_gg,
                                                 d_out, (size_t)E, E, flagp);
        return;
    }

    int* flag = (int*)(ws + off_flag);
    float* params = (float*)(ws + off_params);
    unsigned short* img = (unsigned short*)(ws + off_img);

    prep_kernel<<<33, 256, 0, stream>>>((const unsigned short*)z_gene,
                                        w1_gd, w1_gg, b1_gd, w2_gd, b2_gd,
                                        b1_gg, w2_gg, b2_gg, img, params, flag);

    int nbe = (E + 127) / 128;
    fused_edge_kernel<<<2 * nbe, 512, 0, stream>>>(
        z_gene, z_dis, edges_gd, edges_gg,
        (const uint4*)img, params, d_out, E, nbe, flag);
}

// Round 6
// 282.262 us; speedup vs baseline: 1.0969x; 1.0969x over previous
//
#include <hip/hip_runtime.h>
#include <hip/hip_bf16.h>

#define HDIM 128

typedef __attribute__((ext_vector_type(8))) short short8;
typedef __attribute__((ext_vector_type(4))) float floatx4;

__device__ __forceinline__ float bf2f(unsigned short u) {
    return __uint_as_float(((unsigned)u) << 16);
}
__device__ __forceinline__ unsigned short f2b(float f) {
    __hip_bfloat16 h = __float2bfloat16(f);
    return __builtin_bit_cast(unsigned short, h);
}
__device__ __forceinline__ float ldv(const void* p, size_t i, int flag) {
    return flag ? bf2f(((const unsigned short*)p)[i]) : ((const float*)p)[i];
}
__device__ __forceinline__ short8 pack8(float4 a, float4 b) {
    short8 r;
    r[0] = (short)f2b(a.x); r[1] = (short)f2b(a.y);
    r[2] = (short)f2b(a.z); r[3] = (short)f2b(a.w);
    r[4] = (short)f2b(b.x); r[5] = (short)f2b(b.y);
    r[6] = (short)f2b(b.z); r[7] = (short)f2b(b.w);
    return r;
}

// ---------------------------------------------------------------------------
// Block-local dtype detect. flag=1 -> bf16, 0 -> f32.
// ---------------------------------------------------------------------------
__device__ __forceinline__ int local_detect_s(const unsigned short* zbits, int* red) {
    int tid = threadIdx.x;
    int nthr = blockDim.x;
    int cnt = 0;
    for (int i = tid; i < 4096; i += nthr) {
        int ex = (zbits[i] >> 7) & 0xFF;
        if (ex >= 100 && ex <= 140) cnt++;
    }
    red[tid] = cnt;
    __syncthreads();
    for (int s = nthr >> 1; s > 0; s >>= 1) {
        if (tid < s) red[tid] += red[tid + s];
        __syncthreads();
    }
    int f = (red[0] >= 3686) ? 1 : 0;
    __syncthreads();
    return f;
}

__device__ __forceinline__ int local_detect(const unsigned short* zbits) {
    __shared__ int red[256];
    return local_detect_s(zbits, red);
}

// ---------------------------------------------------------------------------
// prep: blocks 0-31 build swizzled transposed 128x128 bf16 W images with
// COALESCED source reads (scattered 2B writes are fire-and-forget).
// img[im][n*128 + ((k>>3)^(n&15))*8 + (k&7)] = w1[(part*128+k)*128 + n]
// im: 0=gd_top(k=src) 1=gd_bot(k=dst) 2=gg_top 3=gg_bot.
// Block 32: params to f32 + flag:
// [0:128)=b1_gd [128:256)=w2_gd [256:384)=b1_gg [384:512)=w2_gg
// [512]=b2_gd [513]=b2_gg        (verified r0-r2)
// ---------------------------------------------------------------------------
__global__ __launch_bounds__(256) void prep_kernel(
    const unsigned short* __restrict__ zbits,
    const void* __restrict__ w1_gd, const void* __restrict__ w1_gg,
    const void* __restrict__ b1_gd, const void* __restrict__ w2_gd,
    const void* __restrict__ b2_gd, const void* __restrict__ b1_gg,
    const void* __restrict__ w2_gg, const void* __restrict__ b2_gg,
    unsigned short* __restrict__ img, float* __restrict__ params,
    int* __restrict__ flagout)
{
    int flag = local_detect(zbits);
    int b = blockIdx.x;
    int tid = threadIdx.x;
    if (b < 32) {
        int im   = b >> 3;          // image id
        int sub  = b & 7;           // 16 k-rows per sub-block
        const void* w1 = (im < 2) ? w1_gd : w1_gg;
        int part = im & 1;
        unsigned short* out = img + im * 16384;
        int n = tid & 127;
#pragma unroll
        for (int it = 0; it < 8; ++it) {
            int k = sub * 16 + it * 2 + (tid >> 7);
            unsigned short v = flag
                ? ((const unsigned short*)w1)[(size_t)(part * 128 + k) * 128 + n]
                : f2b(((const float*)w1)[(size_t)(part * 128 + k) * 128 + n]);
            out[n * 128 + (((k >> 3) ^ (n & 15)) << 3) + (k & 7)] = v;
        }
    } else {
        if (tid < 128) {
            params[tid]       = ldv(b1_gd, tid, flag);
            params[256 + tid] = ldv(b1_gg, tid, flag);
        } else {
            params[tid]       = ldv(w2_gd, tid - 128, flag);
            params[256 + tid] = ldv(w2_gg, tid - 128, flag);
        }
        if (tid == 0) {
            params[512] = ldv(b2_gd, 0, flag);
            params[513] = ldv(b2_gg, 0, flag);
            *flagout = flag;
        }
    }
}

// ---------------------------------------------------------------------------
// fused_edge v2: per-edge full MLP via MFMA (proj dispatch eliminated).
// out[e] = relu([zsrc;zdst].W1 + b1).w2 + b2
// 512 threads = 8 waves; 16 edges/wave -> 128 edges/block.
//
// r5 lesson (counters): __launch_bounds__(512,4) capped VGPR at 64 ->
// register spills (WRITE_SIZE 113MB of scratch) which also thrashed L2 and
// killed z-row reuse (FETCH 485MB).  LDS (64KB) already caps occupancy at
// 2 blocks/CU = 4 waves/SIMD, which permits 128 VGPRs -> (512,2).
// Gathers are issued BEFORE the W staging loop so their latency hides
// under the LDS copy (vmcnt FIFO: first-issued completes first).
//
// MFMA fragment mapping (verified r0-r2 proj + r5 pass):
//   B-frag lane(nl,quad) kc: z[row(nl)][kc*32+quad*8 ..+8)  (kc<4:src, >=4:dst)
//   A-frag: sW[half][ (nt*16+nl)*16 + ((kc&3)*4+quad)^nl ]
//   C: col=edge=nl, row = quad*4+reg  -> h[edge][nt*16+quad*4+reg]
// ---------------------------------------------------------------------------
__global__ __launch_bounds__(512, 2) void fused_edge_kernel(
    const void* __restrict__ Zg, const void* __restrict__ Zd,
    const int* __restrict__ edges_gd, const int* __restrict__ edges_gg,
    const uint4* __restrict__ Wimg, const float* __restrict__ params,
    void* __restrict__ out, int E, int nbe, const int* __restrict__ flagp)
{
    __shared__ uint4 sW[4096];   // 64 KB: this relation's W1 (two half images)
    int tid  = threadIdx.x;
    int lane = tid & 63;
    int wave = tid >> 6;
    int nl   = lane & 15;   // edge within tile
    int quad = lane >> 4;   // k-subslice / out-channel subslice
    int flag = *flagp;

    int rel = ((int)blockIdx.x >= nbe) ? 1 : 0;
    int blk = blockIdx.x - rel * nbe;
    const int* edges = rel ? edges_gg : edges_gd;
    const void* Zdst = rel ? Zg : Zd;

    // ---- edge indices + B-fragment gathers (issued FIRST: latency hides
    //      under the W staging copy below) ----------------------------------
    int e  = blk * 128 + wave * 16 + nl;
    int ec = e < E ? e : E - 1;
    int src = edges[ec];
    int dst = edges[E + ec];

    short8 zf[8];
    if (flag) {
        const uint4* zs = (const uint4*)Zg   + (size_t)src * 16;
        const uint4* zd = (const uint4*)Zdst + (size_t)dst * 16;
#pragma unroll
        for (int kc = 0; kc < 4; ++kc) {
            zf[kc]     = __builtin_bit_cast(short8, zs[kc * 4 + quad]);
            zf[kc + 4] = __builtin_bit_cast(short8, zd[kc * 4 + quad]);
        }
    } else {
        const float4* zs = (const float4*)Zg   + (size_t)src * 32;
        const float4* zd = (const float4*)Zdst + (size_t)dst * 32;
#pragma unroll
        for (int kc = 0; kc < 4; ++kc) {
            int o = kc * 8 + quad * 2;
            zf[kc]     = pack8(zs[o], zs[o + 1]);
            zf[kc + 4] = pack8(zd[o], zd[o + 1]);
        }
    }

    // ---- stage W images: linear copy, conflict-free, L2-resident ----------
    const uint4* im = Wimg + rel * 4096;
#pragma unroll
    for (int i = 0; i < 8; ++i) sW[tid + i * 512] = im[tid + i * 512];

    __syncthreads();   // W staged

    // ---- MFMA: h[16 edges][128] ------------------------------------------
    floatx4 acc[8];
#pragma unroll
    for (int nt = 0; nt < 8; ++nt) acc[nt] = (floatx4){0.f, 0.f, 0.f, 0.f};

#pragma unroll
    for (int kc = 0; kc < 8; ++kc) {
        const uint4* base = sW + (kc >> 2) * 2048;
        int p = ((kc & 3) * 4 + quad) ^ nl;   // undo XOR swizzle
#pragma unroll
        for (int nt = 0; nt < 8; ++nt) {
            short8 wf = __builtin_bit_cast(short8, base[(nt * 16 + nl) * 16 + p]);
            acc[nt] = __builtin_amdgcn_mfma_f32_16x16x32_bf16(wf, zf[kc], acc[nt], 0, 0, 0);
        }
    }

    // ---- epilogue: bias + relu + dot(w2) + quad reduce --------------------
    const float* pr = params + rel * 256;   // [0:128)=b1, [128:256)=w2
    float b2 = params[512 + rel];
    float s = 0.f;
#pragma unroll
    for (int nt = 0; nt < 8; ++nt) {
        float4 b1v = *(const float4*)(pr + nt * 16 + quad * 4);
        float4 w2v = *(const float4*)(pr + 128 + nt * 16 + quad * 4);
        s = fmaf(fmaxf(acc[nt][0] + b1v.x, 0.f), w2v.x, s);
        s = fmaf(fmaxf(acc[nt][1] + b1v.y, 0.f), w2v.y, s);
        s = fmaf(fmaxf(acc[nt][2] + b1v.z, 0.f), w2v.z, s);
        s = fmaf(fmaxf(acc[nt][3] + b1v.w, 0.f), w2v.w, s);
    }
    s += __shfl_xor(s, 16);
    s += __shfl_xor(s, 32);

    if (quad == 0 && e < E) {
        float r = s + b2;
        size_t base = (size_t)rel * E;
        if (flag) ((unsigned short*)out)[base + e] = f2b(r);
        else      ((float*)out)[base + e] = r;
    }
}

// ---------------------------------------------------------------------------
// Fallback path (ws too small): detect + full per-edge MLP, one edge/block.
// ---------------------------------------------------------------------------
__global__ __launch_bounds__(256) void detect_kernel(
    const unsigned short* __restrict__ zbits, int* __restrict__ flag)
{
    int f = local_detect(zbits);
    if (threadIdx.x == 0) *flag = f;
}

__global__ __launch_bounds__(128) void naive_edge_kernel(
    const int* __restrict__ edges,
    const void* __restrict__ zsrc, const void* __restrict__ zdst,
    const void* __restrict__ w1, const void* __restrict__ b1,
    const void* __restrict__ w2, const void* __restrict__ b2,
    void* __restrict__ out, size_t eoff, int E,
    const int* __restrict__ flagp)
{
    int flag = flagp ? *flagp : 0;
    __shared__ float zs[128], zd[128], red[128];
    int e = blockIdx.x;
    int n = threadIdx.x;
    int src = edges[e], dst = edges[E + e];
    zs[n] = ldv(zsrc, (size_t)src * HDIM + n, flag);
    zd[n] = ldv(zdst, (size_t)dst * HDIM + n, flag);
    __syncthreads();
    float acc = ldv(b1, n, flag);
    for (int k = 0; k < 128; ++k) acc = fmaf(zs[k], ldv(w1, (size_t)k * HDIM + n, flag), acc);
    for (int k = 0; k < 128; ++k) acc = fmaf(zd[k], ldv(w1, (size_t)(128 + k) * HDIM + n, flag), acc);
    red[n] = fmaxf(acc, 0.f) * ldv(w2, n, flag);
    __syncthreads();
    for (int s = 64; s > 0; s >>= 1) {
        if (n < s) red[n] += red[n + s];
        __syncthreads();
    }
    if (n == 0) {
        float r = red[0] + ldv(b2, 0, flag);
        if (flag) ((unsigned short*)out)[eoff + e] = f2b(r);
        else      ((float*)out)[eoff + e] = r;
    }
}

extern "C" void kernel_launch(void* const* d_in, const int* in_sizes, int n_in,
                              void* d_out, int out_size, void* d_ws, size_t ws_size,
                              hipStream_t stream)
{
    const void* z_gene = d_in[0];
    const void* z_dis  = d_in[1];
    const int* edges_gd = (const int*)d_in[2];
    const int* edges_gg = (const int*)d_in[3];
    const void* w1_gd = d_in[4];
    const void* b1_gd = d_in[5];
    const void* w2_gd = d_in[6];
    const void* b2_gd = d_in[7];
    const void* w1_gg = d_in[8];
    const void* b1_gg = d_in[9];
    const void* w2_gg = d_in[10];
    const void* b2_gg = d_in[11];

    int NG = in_sizes[0] / HDIM;   // 100000  (unused in fast path sizing)
    int ND = in_sizes[1] / HDIM;   // 20000
    int E  = in_sizes[2] / 2;      // 500000
    (void)NG; (void)ND;

    // workspace layout (bytes)
    size_t off_flag   = 0;
    size_t off_params = 256;
    size_t off_img    = 2560;
    size_t need       = off_img + 131072;   // flag + params + 4 W images

    char* ws = (char*)d_ws;

    if (ws_size < need) {
        const int* flagp = nullptr;
        if (ws_size >= 16) {
            detect_kernel<<<1, 256, 0, stream>>>((const unsigned short*)z_gene, (int*)ws);
            flagp = (const int*)ws;
        }
        naive_edge_kernel<<<E, 128, 0, stream>>>(edges_gd, z_gene, z_dis,
                                                 w1_gd, b1_gd, w2_gd, b2_gd,
                                                 d_out, 0, E, flagp);
        naive_edge_kernel<<<E, 128, 0, stream>>>(edges_gg, z_gene, z_gene,
                                                 w1_gg, b1_gg, w2_gg, b2_gg,
                                                 d_out, (size_t)E, E, flagp);
        return;
    }

    int* flag = (int*)(ws + off_flag);
    float* params = (float*)(ws + off_params);
    unsigned short* img = (unsigned short*)(ws + off_img);

    prep_kernel<<<33, 256, 0, stream>>>((const unsigned short*)z_gene,
                                        w1_gd, w1_gg, b1_gd, w2_gd, b2_gd,
                                        b1_gg, w2_gg, b2_gg, img, params, flag);

    int nbe = (E + 127) / 128;
    fused_edge_kernel<<<2 * nbe, 512, 0, stream>>>(
        z_gene, z_dis, edges_gd, edges_gg,
        (const uint4*)img, params, d_out, E, nbe, flag);
}

// Round 7
// 227.969 us; speedup vs baseline: 1.3582x; 1.2382x over previous
//
#include <hip/hip_runtime.h>
#include <hip/hip_bf16.h>

#define HDIM 128

typedef __attribute__((ext_vector_type(8))) short short8;
typedef __attribute__((ext_vector_type(4))) float floatx4;

__device__ __forceinline__ float bf2f(unsigned short u) {
    return __uint_as_float(((unsigned)u) << 16);
}
__device__ __forceinline__ unsigned short f2b(float f) {
    __hip_bfloat16 h = __float2bfloat16(f);
    return __builtin_bit_cast(unsigned short, h);
}
__device__ __forceinline__ float ldv(const void* p, size_t i, int flag) {
    return flag ? bf2f(((const unsigned short*)p)[i]) : ((const float*)p)[i];
}
__device__ __forceinline__ short8 pack8(float4 a, float4 b) {
    short8 r;
    r[0] = (short)f2b(a.x); r[1] = (short)f2b(a.y);
    r[2] = (short)f2b(a.z); r[3] = (short)f2b(a.w);
    r[4] = (short)f2b(b.x); r[5] = (short)f2b(b.y);
    r[6] = (short)f2b(b.z); r[7] = (short)f2b(b.w);
    return r;
}

// ---------------------------------------------------------------------------
// Block-local dtype detect. flag=1 -> bf16, 0 -> f32.
// ---------------------------------------------------------------------------
__device__ __forceinline__ int local_detect_s(const unsigned short* zbits, int* red) {
    int tid = threadIdx.x;
    int nthr = blockDim.x;
    int cnt = 0;
    for (int i = tid; i < 4096; i += nthr) {
        int ex = (zbits[i] >> 7) & 0xFF;
        if (ex >= 100 && ex <= 140) cnt++;
    }
    red[tid] = cnt;
    __syncthreads();
    for (int s = nthr >> 1; s > 0; s >>= 1) {
        if (tid < s) red[tid] += red[tid + s];
        __syncthreads();
    }
    int f = (red[0] >= 3686) ? 1 : 0;
    __syncthreads();
    return f;
}

__device__ __forceinline__ int local_detect(const unsigned short* zbits) {
    __shared__ int red[256];
    return local_detect_s(zbits, red);
}

// ---------------------------------------------------------------------------
// prep v2:
//  blocks 0-31 : swizzled transposed 128x128 bf16 W images (verified r0-r2)
//    img[im][n*128 + ((k>>3)^(n&15))*8 + (k&7)] = w1[(part*128+k)*128 + n]
//    im: 0=gd_top(k=src) 1=gd_bot(k=dst) 2=gg_top 3=gg_bot
//  block 32    : params to f32 + flag
//  blocks 33+  : z -> bf16 COMPACTION (r6 lesson: inputs are f32; gathering
//    raw rows costs 512B/row -> FETCH 457MB. Compacting to bf16 first
//    restores the 256B/row gathers the r0-r2 pipeline had via its bf16 A/B
//    tables). flag=1 inputs are already bf16 -> skip (fused reads originals).
//    Grid-stride, fully coalesced: 2x float4 read -> 1x uint4 write / thread.
// ---------------------------------------------------------------------------
__global__ __launch_bounds__(256) void prep_kernel(
    const void* __restrict__ Zg, const void* __restrict__ Zd,
    const void* __restrict__ w1_gd, const void* __restrict__ w1_gg,
    const void* __restrict__ b1_gd, const void* __restrict__ w2_gd,
    const void* __restrict__ b2_gd, const void* __restrict__ b1_gg,
    const void* __restrict__ w2_gg, const void* __restrict__ b2_gg,
    unsigned short* __restrict__ img, float* __restrict__ params,
    int* __restrict__ flagout,
    unsigned short* __restrict__ Zcg, unsigned short* __restrict__ Zcd,
    int NG, int ND)
{
    int flag = local_detect((const unsigned short*)Zg);
    int b = blockIdx.x;
    int tid = threadIdx.x;
    if (b < 32) {
        int im   = b >> 3;          // image id
        int sub  = b & 7;           // 16 k-rows per sub-block
        const void* w1 = (im < 2) ? w1_gd : w1_gg;
        int part = im & 1;
        unsigned short* out = img + im * 16384;
        int n = tid & 127;
#pragma unroll
        for (int it = 0; it < 8; ++it) {
            int k = sub * 16 + it * 2 + (tid >> 7);
            unsigned short v = flag
                ? ((const unsigned short*)w1)[(size_t)(part * 128 + k) * 128 + n]
                : f2b(((const float*)w1)[(size_t)(part * 128 + k) * 128 + n]);
            out[n * 128 + (((k >> 3) ^ (n & 15)) << 3) + (k & 7)] = v;
        }
    } else if (b == 32) {
        if (tid < 128) {
            params[tid]       = ldv(b1_gd, tid, flag);
            params[256 + tid] = ldv(b1_gg, tid, flag);
        } else {
            params[tid]       = ldv(w2_gd, tid - 128, flag);
            params[256 + tid] = ldv(w2_gg, tid - 128, flag);
        }
        if (tid == 0) {
            params[512] = ldv(b2_gd, 0, flag);
            params[513] = ldv(b2_gg, 0, flag);
            *flagout = flag;
        }
    } else {
        // ---- z -> bf16 compaction (only needed for f32 inputs) ------------
        if (flag) return;
        long ng8 = (long)NG * 16;             // 8-elem groups in gene table
        long tot = ng8 + (long)ND * 16;
        long stride = (long)(gridDim.x - 33) * 256;
        for (long g = (long)(b - 33) * 256 + tid; g < tot; g += stride) {
            const float* srcf;
            unsigned short* dstp;
            long off;
            if (g < ng8) { srcf = (const float*)Zg; dstp = Zcg; off = g * 8; }
            else         { srcf = (const float*)Zd; dstp = Zcd; off = (g - ng8) * 8; }
            float4 f0 = *(const float4*)(srcf + off);
            float4 f1 = *(const float4*)(srcf + off + 4);
            short8 v = pack8(f0, f1);
            *(uint4*)(dstp + off) = __builtin_bit_cast(uint4, v);
        }
    }
}

// ---------------------------------------------------------------------------
// fused_edge v3: per-edge full MLP via MFMA (proj dispatch eliminated).
// out[e] = relu([zsrc;zdst].W1 + b1).w2 + b2
// 512 threads = 8 waves; 16 edges/wave -> 128 edges/block.
// Gathers ALWAYS from compact bf16 tables (256B/row): original z when
// flag=1, prep's compacted copy when inputs are f32 (r6: raw f32 gathers
// doubled HBM traffic to 457MB).
// Gathers issued before the W staging copy (latency hides under it).
// MFMA fragment mapping (verified r0-r2 proj + r5/r6 pass):
//   B-frag lane(nl,quad) kc: z[row(nl)][kc*32+quad*8 ..+8)  (kc<4:src, >=4:dst)
//   A-frag: sW[half][ (nt*16+nl)*16 + ((kc&3)*4+quad)^nl ]
//   C: col=edge=nl, row = quad*4+reg  -> h[edge][nt*16+quad*4+reg]
// ---------------------------------------------------------------------------
__global__ __launch_bounds__(512, 2) void fused_edge_kernel(
    const void* __restrict__ Zg, const void* __restrict__ Zd,
    const unsigned short* __restrict__ Zcg, const unsigned short* __restrict__ Zcd,
    const int* __restrict__ edges_gd, const int* __restrict__ edges_gg,
    const uint4* __restrict__ Wimg, const float* __restrict__ params,
    void* __restrict__ out, int E, int nbe, const int* __restrict__ flagp)
{
    __shared__ uint4 sW[4096];   // 64 KB: this relation's W1 (two half images)
    int tid  = threadIdx.x;
    int lane = tid & 63;
    int wave = tid >> 6;
    int nl   = lane & 15;   // edge within tile
    int quad = lane >> 4;   // k-subslice / out-channel subslice
    int flag = *flagp;

    int rel = ((int)blockIdx.x >= nbe) ? 1 : 0;
    int blk = blockIdx.x - rel * nbe;
    const int* edges = rel ? edges_gg : edges_gd;

    // compact bf16 tables: originals if already bf16, else prep's copies
    const unsigned short* Tg = flag ? (const unsigned short*)Zg : Zcg;
    const unsigned short* Td = flag ? (const unsigned short*)Zd : Zcd;
    const unsigned short* Tdst = rel ? Tg : Td;

    // ---- edge indices + B-fragment gathers (issued FIRST) -----------------
    int e  = blk * 128 + wave * 16 + nl;
    int ec = e < E ? e : E - 1;
    int src = edges[ec];
    int dst = edges[E + ec];

    short8 zf[8];
    {
        const uint4* zs = (const uint4*)Tg   + (size_t)src * 16;
        const uint4* zd = (const uint4*)Tdst + (size_t)dst * 16;
#pragma unroll
        for (int kc = 0; kc < 4; ++kc) {
            zf[kc]     = __builtin_bit_cast(short8, zs[kc * 4 + quad]);
            zf[kc + 4] = __builtin_bit_cast(short8, zd[kc * 4 + quad]);
        }
    }

    // ---- stage W images: linear copy, conflict-free, L2/L3-resident -------
    const uint4* im = Wimg + rel * 4096;
#pragma unroll
    for (int i = 0; i < 8; ++i) sW[tid + i * 512] = im[tid + i * 512];

    __syncthreads();   // W staged

    // ---- MFMA: h[16 edges][128] ------------------------------------------
    floatx4 acc[8];
#pragma unroll
    for (int nt = 0; nt < 8; ++nt) acc[nt] = (floatx4){0.f, 0.f, 0.f, 0.f};

#pragma unroll
    for (int kc = 0; kc < 8; ++kc) {
        const uint4* base = sW + (kc >> 2) * 2048;
        int p = ((kc & 3) * 4 + quad) ^ nl;   // undo XOR swizzle
#pragma unroll
        for (int nt = 0; nt < 8; ++nt) {
            short8 wf = __builtin_bit_cast(short8, base[(nt * 16 + nl) * 16 + p]);
            acc[nt] = __builtin_amdgcn_mfma_f32_16x16x32_bf16(wf, zf[kc], acc[nt], 0, 0, 0);
        }
    }

    // ---- epilogue: bias + relu + dot(w2) + quad reduce --------------------
    const float* pr = params + rel * 256;   // [0:128)=b1, [128:256)=w2
    float b2 = params[512 + rel];
    float s = 0.f;
#pragma unroll
    for (int nt = 0; nt < 8; ++nt) {
        float4 b1v = *(const float4*)(pr + nt * 16 + quad * 4);
        float4 w2v = *(const float4*)(pr + 128 + nt * 16 + quad * 4);
        s = fmaf(fmaxf(acc[nt][0] + b1v.x, 0.f), w2v.x, s);
        s = fmaf(fmaxf(acc[nt][1] + b1v.y, 0.f), w2v.y, s);
        s = fmaf(fmaxf(acc[nt][2] + b1v.z, 0.f), w2v.z, s);
        s = fmaf(fmaxf(acc[nt][3] + b1v.w, 0.f), w2v.w, s);
    }
    s += __shfl_xor(s, 16);
    s += __shfl_xor(s, 32);

    if (quad == 0 && e < E) {
        float r = s + b2;
        size_t base = (size_t)rel * E;
        if (flag) ((unsigned short*)out)[base + e] = f2b(r);
        else      ((float*)out)[base + e] = r;
    }
}

// ---------------------------------------------------------------------------
// Fallback path (ws too small): detect + full per-edge MLP, one edge/block.
// ---------------------------------------------------------------------------
__global__ __launch_bounds__(256) void detect_kernel(
    const unsigned short* __restrict__ zbits, int* __restrict__ flag)
{
    int f = local_detect(zbits);
    if (threadIdx.x == 0) *flag = f;
}

__global__ __launch_bounds__(128) void naive_edge_kernel(
    const int* __restrict__ edges,
    const void* __restrict__ zsrc, const void* __restrict__ zdst,
    const void* __restrict__ w1, const void* __restrict__ b1,
    const void* __restrict__ w2, const void* __restrict__ b2,
    void* __restrict__ out, size_t eoff, int E,
    const int* __restrict__ flagp)
{
    int flag = flagp ? *flagp : 0;
    __shared__ float zs[128], zd[128], red[128];
    int e = blockIdx.x;
    int n = threadIdx.x;
    int src = edges[e], dst = edges[E + e];
    zs[n] = ldv(zsrc, (size_t)src * HDIM + n, flag);
    zd[n] = ldv(zdst, (size_t)dst * HDIM + n, flag);
    __syncthreads();
    float acc = ldv(b1, n, flag);
    for (int k = 0; k < 128; ++k) acc = fmaf(zs[k], ldv(w1, (size_t)k * HDIM + n, flag), acc);
    for (int k = 0; k < 128; ++k) acc = fmaf(zd[k], ldv(w1, (size_t)(128 + k) * HDIM + n, flag), acc);
    red[n] = fmaxf(acc, 0.f) * ldv(w2, n, flag);
    __syncthreads();
    for (int s = 64; s > 0; s >>= 1) {
        if (n < s) red[n] += red[n + s];
        __syncthreads();
    }
    if (n == 0) {
        float r = red[0] + ldv(b2, 0, flag);
        if (flag) ((unsigned short*)out)[eoff + e] = f2b(r);
        else      ((float*)out)[eoff + e] = r;
    }
}

extern "C" void kernel_launch(void* const* d_in, const int* in_sizes, int n_in,
                              void* d_out, int out_size, void* d_ws, size_t ws_size,
                              hipStream_t stream)
{
    const void* z_gene = d_in[0];
    const void* z_dis  = d_in[1];
    const int* edges_gd = (const int*)d_in[2];
    const int* edges_gg = (const int*)d_in[3];
    const void* w1_gd = d_in[4];
    const void* b1_gd = d_in[5];
    const void* w2_gd = d_in[6];
    const void* b2_gd = d_in[7];
    const void* w1_gg = d_in[8];
    const void* b1_gg = d_in[9];
    const void* w2_gg = d_in[10];
    const void* b2_gg = d_in[11];

    int NG = in_sizes[0] / HDIM;   // 100000
    int ND = in_sizes[1] / HDIM;   // 20000
    int E  = in_sizes[2] / 2;      // 500000

    // workspace layout (bytes)
    size_t off_flag   = 0;
    size_t off_params = 256;
    size_t off_img    = 2560;
    size_t off_Zcg    = off_img + 131072;
    size_t off_Zcd    = off_Zcg + (size_t)NG * HDIM * 2;
    size_t need       = off_Zcd + (size_t)ND * HDIM * 2;

    char* ws = (char*)d_ws;

    if (ws_size < need) {
        const int* flagp = nullptr;
        if (ws_size >= 16) {
            detect_kernel<<<1, 256, 0, stream>>>((const unsigned short*)z_gene, (int*)ws);
            flagp = (const int*)ws;
        }
        naive_edge_kernel<<<E, 128, 0, stream>>>(edges_gd, z_gene, z_dis,
                                                 w1_gd, b1_gd, w2_gd, b2_gd,
                                                 d_out, 0, E, flagp);
        naive_edge_kernel<<<E, 128, 0, stream>>>(edges_gg, z_gene, z_gene,
                                                 w1_gg, b1_gg, w2_gg, b2_gg,
                                                 d_out, (size_t)E, E, flagp);
        return;
    }

    int* flag = (int*)(ws + off_flag);
    float* params = (float*)(ws + off_params);
    unsigned short* img = (unsigned short*)(ws + off_img);
    unsigned short* Zcg = (unsigned short*)(ws + off_Zcg);
    unsigned short* Zcd = (unsigned short*)(ws + off_Zcd);

    prep_kernel<<<33 + 512, 256, 0, stream>>>(
        z_gene, z_dis,
        w1_gd, w1_gg, b1_gd, w2_gd, b2_gd, b1_gg, w2_gg, b2_gg,
        img, params, flag, Zcg, Zcd, NG, ND);

    int nbe = (E + 127) / 128;
    fused_edge_kernel<<<2 * nbe, 512, 0, stream>>>(
        z_gene, z_dis, Zcg, Zcd, edges_gd, edges_gg,
        (const uint4*)img, params, d_out, E, nbe, flag);
}